// Round 1
// baseline (4135.994 us; speedup 1.0000x reference)
//
#include <hip/hip_runtime.h>
#include <hip/hip_bf16.h>
#include <stdint.h>

// GPT-1 style transformer forward, MI355X bf16-MFMA implementation.
// B=16 S=512 D=768 H=12 L=12 V=40990, out = [13, B, S, D] fp32.

#define B_    16
#define S_    512
#define D_    768
#define H_    12
#define L_    12
#define DH_   64
#define FF_   3072
#define TD_   2304          // 3*D
#define ROWS_ 8192          // B*S

typedef __hip_bfloat16 bf16_t;
typedef __bf16 bf16x8 __attribute__((ext_vector_type(8)));
typedef float  f32x4  __attribute__((ext_vector_type(4)));

static __device__ __forceinline__ bf16_t f2bf(float v) { return __float2bfloat16(v); }

// ---------------------------------------------------------------------------
// int64-vs-int32 detector for x: if stored as int64, every odd int32 word
// (high half) of the first 64 elements is 0.  flag=1 -> int64 layout.
__global__ void detect_kernel(const int* __restrict__ x, int* __restrict__ flag) {
    int v = x[threadIdx.x * 2 + 1];
    unsigned long long m = __ballot(v != 0);
    if (threadIdx.x == 0) *flag = (m == 0ULL) ? 1 : 0;
}

// ---------------------------------------------------------------------------
// Embedding: h0[b,s,:] = we[x[b,s,0]] + we[x[b,s,1]]  (fp32 out + bf16 copy)
__global__ __launch_bounds__(192)
void embed_kernel(const int* __restrict__ x, const int* __restrict__ flag,
                  const float* __restrict__ we,
                  float* __restrict__ out0, bf16_t* __restrict__ hb) {
    int row = blockIdx.x;           // 0..8191
    int tid = threadIdx.x;          // 0..191, 4 floats each
    int mode = *flag;
    int i0, i1;
    if (mode) { i0 = x[row * 4]; i1 = x[row * 4 + 2]; }
    else      { i0 = x[row * 2]; i1 = x[row * 2 + 1]; }
    const float4 a = *(const float4*)(we + (size_t)i0 * D_ + tid * 4);
    const float4 b = *(const float4*)(we + (size_t)i1 * D_ + tid * 4);
    float4 v;
    v.x = a.x + b.x; v.y = a.y + b.y; v.z = a.z + b.z; v.w = a.w + b.w;
    size_t o = (size_t)row * D_ + tid * 4;
    *(float4*)(out0 + o) = v;
    hb[o + 0] = f2bf(v.x); hb[o + 1] = f2bf(v.y);
    hb[o + 2] = f2bf(v.z); hb[o + 3] = f2bf(v.w);
}

// ---------------------------------------------------------------------------
// fp32 [R][C] -> bf16 [C][R]  (weight transpose + downconvert), 32x32 tiles.
__global__ __launch_bounds__(256)
void transpose_cvt_kernel(const float* __restrict__ in, bf16_t* __restrict__ out,
                          int R, int C) {
    __shared__ float tile[32][33];
    int c0 = blockIdx.x * 32, r0 = blockIdx.y * 32;
    int tx = threadIdx.x, ty = threadIdx.y;   // (32, 8)
#pragma unroll
    for (int i = 0; i < 32; i += 8)
        tile[ty + i][tx] = in[(size_t)(r0 + ty + i) * C + c0 + tx];
    __syncthreads();
#pragma unroll
    for (int i = 0; i < 32; i += 8)
        out[(size_t)(c0 + ty + i) * R + r0 + tx] = f2bf(tile[tx][ty + i]);
}

// ---------------------------------------------------------------------------
// GEMM: C[M,N] = A[M,K] * Bt[N,K]^T + bias, optional GELU, out bf16 or f32.
// 128x128 tile, 4 waves (2x2) of 64x64, BK=32, 16x16x32 bf16 MFMA.
template<int OUT_BF16, int GELU>
__global__ __launch_bounds__(256, 2)
void gemm_bt_kernel(const bf16_t* __restrict__ A, const bf16_t* __restrict__ Bt,
                    const float* __restrict__ bias, void* __restrict__ outp,
                    int N, int K) {
    __shared__ bf16_t As[128 * 32];     // [m][k]
    __shared__ bf16_t Bs[128 * 32];     // [n][k]
    const int tid  = threadIdx.x;
    const int wave = tid >> 6, lane = tid & 63;
    const int l15  = lane & 15, l4 = lane >> 4;
    const int bn = blockIdx.x * 128;
    const int bm = blockIdx.y * 128;
    const int wm = (wave >> 1) * 64, wn = (wave & 1) * 64;

    const bf16_t* Ag = A  + (size_t)bm * K;
    const bf16_t* Bg = Bt + (size_t)bn * K;

    f32x4 acc[4][4];
#pragma unroll
    for (int i = 0; i < 4; i++)
#pragma unroll
        for (int j = 0; j < 4; j++) acc[i][j] = (f32x4){0.f, 0.f, 0.f, 0.f};

    // staging: 512 chunks of 8 bf16 (16B); chunk ch -> row ch>>2, col (ch&3)*8
    const int ch0 = tid, ch1 = tid + 256;
    const bf16_t* agp0 = Ag + (size_t)(ch0 >> 2) * K + (ch0 & 3) * 8;
    const bf16_t* agp1 = Ag + (size_t)(ch1 >> 2) * K + (ch1 & 3) * 8;
    const bf16_t* bgp0 = Bg + (size_t)(ch0 >> 2) * K + (ch0 & 3) * 8;
    const bf16_t* bgp1 = Bg + (size_t)(ch1 >> 2) * K + (ch1 & 3) * 8;

    for (int k0 = 0; k0 < K; k0 += 32) {
        uint4 a0 = *(const uint4*)(agp0 + k0);
        uint4 a1 = *(const uint4*)(agp1 + k0);
        uint4 b0 = *(const uint4*)(bgp0 + k0);
        uint4 b1 = *(const uint4*)(bgp1 + k0);
        __syncthreads();                       // prev tile reads done
        *(uint4*)(As + ch0 * 8) = a0;
        *(uint4*)(As + ch1 * 8) = a1;
        *(uint4*)(Bs + ch0 * 8) = b0;
        *(uint4*)(Bs + ch1 * 8) = b1;
        __syncthreads();
        bf16x8 af[4], bfv[4];
#pragma unroll
        for (int mi = 0; mi < 4; mi++)
            af[mi] = *(const bf16x8*)(As + (wm + mi * 16 + l15) * 32 + l4 * 8);
#pragma unroll
        for (int ni = 0; ni < 4; ni++)
            bfv[ni] = *(const bf16x8*)(Bs + (wn + ni * 16 + l15) * 32 + l4 * 8);
#pragma unroll
        for (int mi = 0; mi < 4; mi++)
#pragma unroll
            for (int ni = 0; ni < 4; ni++)
                acc[mi][ni] = __builtin_amdgcn_mfma_f32_16x16x32_bf16(
                    af[mi], bfv[ni], acc[mi][ni], 0, 0, 0);
    }

    // epilogue: C/D layout col=lane&15, row=(lane>>4)*4+reg  (m89-verified)
#pragma unroll
    for (int mi = 0; mi < 4; mi++) {
#pragma unroll
        for (int ni = 0; ni < 4; ni++) {
            int n = bn + wn + ni * 16 + l15;
            float bv = bias[n];
#pragma unroll
            for (int r = 0; r < 4; r++) {
                int m = bm + wm + mi * 16 + l4 * 4 + r;
                float v = acc[mi][ni][r] + bv;
                if (GELU) {
                    float xx = v;
                    float u  = 0.7978845608028654f * (xx + 0.044715f * xx * xx * xx);
                    float au = fabsf(u);
                    float e  = __expf(-2.f * au);           // no overflow
                    float th = (1.f - e) / (1.f + e);
                    th = copysignf(th, u);
                    v = 0.5f * xx * (1.f + th);
                }
                if (OUT_BF16) ((bf16_t*)outp)[(size_t)m * N + n] = f2bf(v);
                else          ((float*) outp)[(size_t)m * N + n] = v;
            }
        }
    }
}

// ---------------------------------------------------------------------------
// Flash attention, causal, S=512, DH=64.  Block = (b,h) x 64 q-rows; 4 waves
// each own 16 q-rows.  KV tiles of 64 staged in LDS (V transposed).
#define AP 72   // LDS row pitch (elems): 144B rows, 16B-aligned, 2-way banks

__global__ __launch_bounds__(256, 2)
void attn_kernel(const bf16_t* __restrict__ qkv, bf16_t* __restrict__ attn_out) {
    __shared__ bf16_t Ks[64 * AP];        // [key][dh]
    __shared__ bf16_t Vt[64 * AP];        // [dh][key]
    __shared__ bf16_t Ps[4][16 * AP];     // per-wave [q][key]
    const int qb   = blockIdx.x;          // 0..7
    const int bh   = blockIdx.y;          // 0..191
    const int b    = bh / H_, h = bh % H_;
    const int tid  = threadIdx.x, wave = tid >> 6, lane = tid & 63;
    const int l15  = lane & 15, l4 = lane >> 4;
    const bf16_t* base = qkv + (size_t)b * S_ * TD_;
    const int q0w = qb * 64 + wave * 16;

    bf16x8 qf0, qf1;
    {
        const bf16_t* qp = base + (size_t)(q0w + l15) * TD_ + h * 64 + l4 * 8;
        qf0 = *(const bf16x8*)(qp);
        qf1 = *(const bf16x8*)(qp + 32);
    }
    f32x4 accO[4];
#pragma unroll
    for (int i = 0; i < 4; i++) accO[i] = (f32x4){0.f, 0.f, 0.f, 0.f};
    float m_run[4] = {-3e38f, -3e38f, -3e38f, -3e38f};
    float l_run[4] = {0.f, 0.f, 0.f, 0.f};

    const int sr = tid >> 2;            // staging row 0..63
    const int sc = (tid & 3) * 16;      // staging col {0,16,32,48}
    const bf16_t* kp_base = base + (size_t)sr * TD_ + D_ + h * 64 + sc;

    for (int t = 0; t <= qb; ++t) {
        int kv0 = t * 64;
        const bf16_t* kp = kp_base + (size_t)kv0 * TD_;
        uint4 ka = *(const uint4*)(kp);
        uint4 kb = *(const uint4*)(kp + 8);
        uint4 va = *(const uint4*)(kp + D_);
        uint4 vb = *(const uint4*)(kp + D_ + 8);
        __syncthreads();                 // prev tile LDS reads done
        *(uint4*)(Ks + sr * AP + sc)     = ka;
        *(uint4*)(Ks + sr * AP + sc + 8) = kb;
        {
            uint16_t* Vs16 = (uint16_t*)Vt;
            const uint16_t* v1 = (const uint16_t*)&va;
            const uint16_t* v2 = (const uint16_t*)&vb;
#pragma unroll
            for (int j = 0; j < 8; j++) Vs16[(sc + j) * AP + sr]     = v1[j];
#pragma unroll
            for (int j = 0; j < 8; j++) Vs16[(sc + 8 + j) * AP + sr] = v2[j];
        }
        __syncthreads();

        // S = Q K^T  (per wave, 16 q-rows x 64 keys)
        f32x4 s[4];
#pragma unroll
        for (int nc = 0; nc < 4; nc++) {
            bf16x8 k0f = *(const bf16x8*)(Ks + (nc * 16 + l15) * AP + l4 * 8);
            bf16x8 k1f = *(const bf16x8*)(Ks + (nc * 16 + l15) * AP + 32 + l4 * 8);
            f32x4 a = (f32x4){0.f, 0.f, 0.f, 0.f};
            a = __builtin_amdgcn_mfma_f32_16x16x32_bf16(qf0, k0f, a, 0, 0, 0);
            a = __builtin_amdgcn_mfma_f32_16x16x32_bf16(qf1, k1f, a, 0, 0, 0);
            s[nc] = a;
        }
        // scale + causal mask + row max
        float mt[4] = {-3e38f, -3e38f, -3e38f, -3e38f};
#pragma unroll
        for (int nc = 0; nc < 4; nc++) {
            int key = kv0 + nc * 16 + l15;
#pragma unroll
            for (int r = 0; r < 4; r++) {
                int q = q0w + l4 * 4 + r;
                float v = s[nc][r] * 0.125f;
                if (key > q) v = -1e9f;
                s[nc][r] = v;
                mt[r] = fmaxf(mt[r], v);
            }
        }
#pragma unroll
        for (int o = 1; o < 16; o <<= 1) {
#pragma unroll
            for (int r = 0; r < 4; r++) mt[r] = fmaxf(mt[r], __shfl_xor(mt[r], o));
        }
        float alpha[4];
#pragma unroll
        for (int r = 0; r < 4; r++) {
            float mn = fmaxf(m_run[r], mt[r]);
            alpha[r] = __expf(m_run[r] - mn);
            m_run[r] = mn;
        }
        float rs[4] = {0.f, 0.f, 0.f, 0.f};
#pragma unroll
        for (int nc = 0; nc < 4; nc++)
#pragma unroll
            for (int r = 0; r < 4; r++) {
                float pv = __expf(s[nc][r] - m_run[r]);
                s[nc][r] = pv;
                rs[r] += pv;
            }
#pragma unroll
        for (int o = 1; o < 16; o <<= 1) {
#pragma unroll
            for (int r = 0; r < 4; r++) rs[r] += __shfl_xor(rs[r], o);
        }
#pragma unroll
        for (int r = 0; r < 4; r++) l_run[r] = l_run[r] * alpha[r] + rs[r];
#pragma unroll
        for (int nc = 0; nc < 4; nc++)
#pragma unroll
            for (int r = 0; r < 4; r++) accO[nc][r] *= alpha[r];

        // P -> per-wave LDS (explicit (q,key) coords; layout-assumption free)
#pragma unroll
        for (int nc = 0; nc < 4; nc++)
#pragma unroll
            for (int r = 0; r < 4; r++)
                Ps[wave][(l4 * 4 + r) * AP + nc * 16 + l15] = f2bf(s[nc][r]);

        // O += P V
        bf16x8 pa0 = *(const bf16x8*)(&Ps[wave][l15 * AP + l4 * 8]);
        bf16x8 pa1 = *(const bf16x8*)(&Ps[wave][l15 * AP + 32 + l4 * 8]);
#pragma unroll
        for (int nc = 0; nc < 4; nc++) {
            bf16x8 v0f = *(const bf16x8*)(Vt + (nc * 16 + l15) * AP + l4 * 8);
            bf16x8 v1f = *(const bf16x8*)(Vt + (nc * 16 + l15) * AP + 32 + l4 * 8);
            accO[nc] = __builtin_amdgcn_mfma_f32_16x16x32_bf16(pa0, v0f, accO[nc], 0, 0, 0);
            accO[nc] = __builtin_amdgcn_mfma_f32_16x16x32_bf16(pa1, v1f, accO[nc], 0, 0, 0);
        }
    }

    // epilogue: O / l, write bf16 at [b][q][h*64 + d]
#pragma unroll
    for (int nc = 0; nc < 4; nc++) {
#pragma unroll
        for (int r = 0; r < 4; r++) {
            int q = q0w + l4 * 4 + r;
            float v = accO[nc][r] / l_run[r];
            attn_out[((size_t)b * S_ + q) * D_ + h * 64 + nc * 16 + l15] = f2bf(v);
        }
    }
}

// ---------------------------------------------------------------------------
// LayerNorm over D=768: t = x1 + x2; y = (t-mu)*rsqrt(var+eps)*g + b.
// Writes fp32 and bf16 copies.
__global__ __launch_bounds__(256)
void ln_kernel(const float* __restrict__ x1, const float* __restrict__ x2,
               const float* __restrict__ g, const float* __restrict__ bta,
               float* __restrict__ outf, bf16_t* __restrict__ outb) {
    __shared__ float red[8];
    int row = blockIdx.x, tid = threadIdx.x;
    const float* p1 = x1 + (size_t)row * D_;
    const float* p2 = x2 + (size_t)row * D_;
    float v[3], s = 0.f, ss = 0.f;
#pragma unroll
    for (int i = 0; i < 3; i++) {
        int c = tid + i * 256;
        v[i] = p1[c] + p2[c];
        s += v[i]; ss += v[i] * v[i];
    }
#pragma unroll
    for (int o = 1; o < 64; o <<= 1) { s += __shfl_xor(s, o); ss += __shfl_xor(ss, o); }
    int wave = tid >> 6, lane = tid & 63;
    if (lane == 0) { red[wave] = s; red[4 + wave] = ss; }
    __syncthreads();
    float S  = red[0] + red[1] + red[2] + red[3];
    float SS = red[4] + red[5] + red[6] + red[7];
    float mu  = S * (1.f / 768.f);
    float var = SS * (1.f / 768.f) - mu * mu;
    float rsv = rsqrtf(var + 1e-5f);
#pragma unroll
    for (int i = 0; i < 3; i++) {
        int c = tid + i * 256;
        float y = (v[i] - mu) * rsv * g[c] + bta[c];
        outf[(size_t)row * D_ + c] = y;
        outb[(size_t)row * D_ + c] = f2bf(y);
    }
}

// ---------------------------------------------------------------------------
extern "C" void kernel_launch(void* const* d_in, const int* in_sizes, int n_in,
                              void* d_out, int out_size, void* d_ws, size_t ws_size,
                              hipStream_t stream) {
    const int*   x   = (const int*)  d_in[0];
    const float* we  = (const float*)d_in[1];
    const float* caw = (const float*)d_in[2];
    const float* cab = (const float*)d_in[3];
    const float* apw = (const float*)d_in[4];
    const float* apb = (const float*)d_in[5];
    const float* g1  = (const float*)d_in[6];
    const float* b1  = (const float*)d_in[7];
    const float* fw  = (const float*)d_in[8];
    const float* fb  = (const float*)d_in[9];
    const float* pw  = (const float*)d_in[10];
    const float* pb  = (const float*)d_in[11];
    const float* g2  = (const float*)d_in[12];
    const float* b2  = (const float*)d_in[13];
    float* out = (float*)d_out;

    char* p = (char*)d_ws;
    auto take = [&](size_t bytes) -> char* {
        char* q = p; p += (bytes + 255) & ~(size_t)255; return q;
    };
    int*    flag  = (int*)   take(256);
    bf16_t* cawt  = (bf16_t*)take((size_t)TD_ * D_ * 2);   // [3D][D] per-layer
    bf16_t* apwt  = (bf16_t*)take((size_t)D_  * D_ * 2);
    bf16_t* fwt   = (bf16_t*)take((size_t)FF_ * D_ * 2);
    bf16_t* pwt   = (bf16_t*)take((size_t)D_  * FF_ * 2);
    bf16_t* hb    = (bf16_t*)take((size_t)ROWS_ * D_  * 2);
    bf16_t* qkvg  = (bf16_t*)take((size_t)ROWS_ * FF_ * 2); // qkv (2304) / gelu (3072)
    bf16_t* attnb = (bf16_t*)take((size_t)ROWS_ * D_  * 2);
    float*  tmpf  = (float*) take((size_t)ROWS_ * D_  * 4);
    float*  nf    = (float*) take((size_t)ROWS_ * D_  * 4);
    bf16_t* nb    = (bf16_t*)take((size_t)ROWS_ * D_  * 2);

    const size_t SLICE = (size_t)ROWS_ * D_;

    detect_kernel<<<1, 64, 0, stream>>>(x, flag);
    embed_kernel<<<ROWS_, 192, 0, stream>>>(x, flag, we, out, hb);

    for (int l = 0; l < L_; ++l) {
        transpose_cvt_kernel<<<dim3(72, 24), dim3(32, 8), 0, stream>>>(
            caw + (size_t)l * D_ * TD_, cawt, D_, TD_);
        transpose_cvt_kernel<<<dim3(24, 24), dim3(32, 8), 0, stream>>>(
            apw + (size_t)l * D_ * D_, apwt, D_, D_);
        transpose_cvt_kernel<<<dim3(96, 24), dim3(32, 8), 0, stream>>>(
            fw + (size_t)l * D_ * FF_, fwt, D_, FF_);
        transpose_cvt_kernel<<<dim3(24, 96), dim3(32, 8), 0, stream>>>(
            pw + (size_t)l * FF_ * D_, pwt, FF_, D_);

        const float* hin = out + (size_t)l * SLICE;
        // qkv = h @ caw + cab           [8192,768] x [768,2304] -> bf16
        gemm_bt_kernel<1, 0><<<dim3(TD_ / 128, ROWS_ / 128), 256, 0, stream>>>(
            hb, cawt, cab + l * TD_, qkvg, TD_, D_);
        // attention
        attn_kernel<<<dim3(8, B_ * H_), 256, 0, stream>>>(qkvg, attnb);
        // a = attn @ apw + apb          -> fp32
        gemm_bt_kernel<0, 0><<<dim3(D_ / 128, ROWS_ / 128), 256, 0, stream>>>(
            attnb, apwt, apb + l * D_, tmpf, D_, D_);
        // n = LN(h + a)
        ln_kernel<<<ROWS_, 256, 0, stream>>>(hin, tmpf, g1 + l * D_, b1 + l * D_, nf, nb);
        // gelu(n @ fw + fb)             -> bf16
        gemm_bt_kernel<1, 1><<<dim3(FF_ / 128, ROWS_ / 128), 256, 0, stream>>>(
            nb, fwt, fb + l * FF_, qkvg, FF_, D_);
        // m = gelu @ pw + pb            -> fp32
        gemm_bt_kernel<0, 0><<<dim3(D_ / 128, ROWS_ / 128), 256, 0, stream>>>(
            qkvg, pwt, pb + l * D_, tmpf, D_, FF_);
        // out[l+1] = LN(n + m)  (+ bf16 h for next layer)
        ln_kernel<<<ROWS_, 256, 0, stream>>>(nf, tmpf, g2 + l * D_, b2 + l * D_,
                                             out + (size_t)(l + 1) * SLICE, hb);
    }
}